// Round 4
// baseline (1089.731 us; speedup 1.0000x reference)
//
#include <hip/hip_runtime.h>
#include <cfloat>

// VQ forward, MI355X. z[16,256,32,32] f32, emb[8192,256] f32, proj[256,256] f32.
// N = 16384 rows, K = 8192 codes, D = 256.
// d_out (floats): out[4194304] | loss | commitment | codebook_loss | idx_as_float[16384]
// d_ws: cbT[256][8192] | cb[8192][256] | norms[8192] | packed_u64[16384] | ssum | znorm[16384]
//
// Correctness-critical: reference rounds d = (||z||^2 + ||e||^2) - 2*dot in fp32,
// quantizing scores to ulp(~256) ~ 1.5e-5; ties resolved by np.argmin first-index.
// We emulate the rounding exactly and tie-break via packed (monof(s)<<32|k) atomicMin.
// k_argmin R4: z comes straight from global (16-way broadcast loads, VMEM pipe);
// only the codebook tile lives in LDS -> LDS pipe at ~31% instead of ~110%.

constexpr int Dd = 256;
constexpr int Kc = 8192;
constexpr float INV_M = 1.0f / 4194304.0f;

#define GLOBAL_AS __attribute__((address_space(1)))
#define LDS_AS    __attribute__((address_space(3)))

__device__ __forceinline__ unsigned monof(float f) {
  unsigned u = __float_as_uint(f);
  return (u & 0x80000000u) ? ~u : (u | 0x80000000u);
}

// ---- K1: codebook = emb @ proj^T, written as cb[k][d] and cbT[d][k] ----
__global__ __launch_bounds__(256)
void k_codebook(const float* __restrict__ emb, const float* __restrict__ proj,
                float* __restrict__ cb, float* __restrict__ cbT) {
  __shared__ float et[64 * 65];
  __shared__ float pt[64 * 65];
  const int t = threadIdx.x;
  const int tx = t & 15, ty = t >> 4;
  const int kb = blockIdx.x * 64;
  const int db = blockIdx.y * 64;
  float acc[4][4];
#pragma unroll
  for (int u = 0; u < 4; ++u)
#pragma unroll
    for (int v = 0; v < 4; ++v) acc[u][v] = 0.f;

  const int jm = t & 15;
  const int q  = t >> 4;

  for (int jc = 0; jc < Dd; jc += 64) {
    __syncthreads();
#pragma unroll
    for (int i = 0; i < 4; ++i) {
      const int row = q + i * 16;
      const float4 e4 = *(const float4*)(emb  + (size_t)(kb + row) * Dd + jc + jm * 4);
      const float4 p4 = *(const float4*)(proj + (size_t)(db + row) * Dd + jc + jm * 4);
      et[(jm*4 + 0) * 65 + row] = e4.x;
      et[(jm*4 + 1) * 65 + row] = e4.y;
      et[(jm*4 + 2) * 65 + row] = e4.z;
      et[(jm*4 + 3) * 65 + row] = e4.w;
      pt[(jm*4 + 0) * 65 + row] = p4.x;
      pt[(jm*4 + 1) * 65 + row] = p4.y;
      pt[(jm*4 + 2) * 65 + row] = p4.z;
      pt[(jm*4 + 3) * 65 + row] = p4.w;
    }
    __syncthreads();
#pragma unroll 16
    for (int j = 0; j < 64; ++j) {
      float a[4], b[4];
#pragma unroll
      for (int u = 0; u < 4; ++u) a[u] = et[j*65 + ty*4 + u];
#pragma unroll
      for (int v = 0; v < 4; ++v) b[v] = pt[j*65 + tx*4 + v];
#pragma unroll
      for (int u = 0; u < 4; ++u)
#pragma unroll
        for (int v = 0; v < 4; ++v) acc[u][v] = fmaf(a[u], b[v], acc[u][v]);
    }
  }
#pragma unroll
  for (int u = 0; u < 4; ++u) {
    const int k = kb + ty*4 + u;
#pragma unroll
    for (int v = 0; v < 4; ++v) {
      const int d = db + tx*4 + v;
      cb [(size_t)k * Dd + d] = acc[u][v];
      cbT[(size_t)d * Kc + k] = acc[u][v];
    }
  }
}

// ---- K1b: per-code squared norms ----
__global__ __launch_bounds__(256)
void k_norms(const float* __restrict__ cbT, float* __restrict__ norms) {
  const int k = blockIdx.x * 256 + threadIdx.x;
  float s = 0.f;
  for (int d = 0; d < Dd; ++d) {
    const float v = cbT[(size_t)d * Kc + k];
    s = fmaf(v, v, s);
  }
  norms[k] = s;
}

// ---- K1c: per-row ||z||^2, computed ONCE so all argmin blocks see identical bits ----
__global__ __launch_bounds__(256)
void k_znorm(const float* __restrict__ z, float* __restrict__ znorm) {
  const int n = blockIdx.x * 256 + threadIdx.x;
  const float* p = z + (size_t)(n >> 10) * 262144 + (n & 1023);
  float s = 0.f;
  for (int d = 0; d < Dd; ++d) {
    const float v = p[(size_t)d * 1024];
    s = fmaf(v, v, s);
  }
  znorm[n] = s;
}

// ---- K2: fused distance + argmin.  256 rows x (8 kt x 128 cols) per block ----
// Per-thread 16 rows x 8 cols.  z fragments: global broadcast loads (one 64 B
// line per load, L1/L2-resident slab).  e fragments: LDS, staged via
// global_load_lds width=16, conflict-free b128 reads (verified 0 conflicts R3).
__global__ __launch_bounds__(256, 2)
void k_argmin(const float* __restrict__ z, const float* __restrict__ cbT,
              const float* __restrict__ norms, const float* __restrict__ znorm,
              unsigned long long* __restrict__ packed) {
  __shared__ float es[32 * 128];   // [j][128 cols]  16 KB (only LDS user)
  const int t    = threadIdx.x;
  const int tx   = t & 15;         // col group
  const int ty   = t >> 4;         // row group (0..15)
  const int lane = t & 63;
  const int wv   = t >> 6;         // wave 0..3
  const int nbase = blockIdx.y * 256;   // 256-aligned => single b, contiguous hw
  const int kbase = blockIdx.x * 1024;
  const float* zb = z + (size_t)(nbase >> 10) * 262144 + (nbase & 1023);

  // per-thread rows: r = s*64 + ty*4 + rr  (s=0..3, rr=0..3)
  float zn[4][4];
#pragma unroll
  for (int s = 0; s < 4; ++s)
#pragma unroll
    for (int rr = 0; rr < 4; ++rr)
      zn[s][rr] = znorm[nbase + s * 64 + ty * 4 + rr];

  float mv[4][4];
  int   mi[4][4];
#pragma unroll
  for (int s = 0; s < 4; ++s)
#pragma unroll
    for (int rr = 0; rr < 4; ++rr) { mv[s][rr] = FLT_MAX; mi[s][rr] = 0; }

#pragma unroll 1
  for (int kt = 0; kt < 8; ++kt) {
    const int kstart = kbase + kt * 128;
    float acc[4][4][2][4];
#pragma unroll
    for (int s = 0; s < 4; ++s)
#pragma unroll
      for (int rr = 0; rr < 4; ++rr)
#pragma unroll
        for (int h = 0; h < 2; ++h)
#pragma unroll
          for (int cc = 0; cc < 4; ++cc) acc[s][rr][h][cc] = 0.f;

#pragma unroll 1
    for (int dc = 0; dc < Dd; dc += 32) {
      __syncthreads();
      // es: 16 KB as 16 wave-instrs of 1024 B; instr q covers j-pair (2q,2q+1)
#pragma unroll
      for (int i = 0; i < 4; ++i) {
        const int q = wv * 4 + i;
        const float* gp = cbT + (size_t)(dc + 2 * q + (lane >> 5)) * Kc
                              + kstart + (lane & 31) * 4;
        __builtin_amdgcn_global_load_lds(
            (const GLOBAL_AS void*)gp,
            (LDS_AS void*)(es + q * 256), 16, 0, 0);
      }
      __syncthreads();

#pragma unroll 4
      for (int j = 0; j < 32; ++j) {
        // z fragment straight from global: 4 loads, each 16-way broadcast
        // (one 64 B line per load) -> VMEM pipe, L1/L2 hit.
        const float* zrow = zb + (size_t)(dc + j) * 1024 + ty * 4;
        float4 za[4];
#pragma unroll
        for (int s = 0; s < 4; ++s)
          za[s] = *(const float4*)(zrow + s * 64);
        float4 ea[2];
#pragma unroll
        for (int h = 0; h < 2; ++h)
          ea[h] = *(const float4*)(es + j * 128 + h * 64 + tx * 4);
        const float zr[4][4] = {{za[0].x,za[0].y,za[0].z,za[0].w},
                                {za[1].x,za[1].y,za[1].z,za[1].w},
                                {za[2].x,za[2].y,za[2].z,za[2].w},
                                {za[3].x,za[3].y,za[3].z,za[3].w}};
        const float er[2][4] = {{ea[0].x,ea[0].y,ea[0].z,ea[0].w},
                                {ea[1].x,ea[1].y,ea[1].z,ea[1].w}};
#pragma unroll
        for (int s = 0; s < 4; ++s)
#pragma unroll
          for (int rr = 0; rr < 4; ++rr)
#pragma unroll
            for (int h = 0; h < 2; ++h)
#pragma unroll
              for (int cc = 0; cc < 4; ++cc)
                acc[s][rr][h][cc] =
                    fmaf(zr[s][rr], er[h][cc], acc[s][rr][h][cc]);
      }
    }
    // Quantized fold: s = fl( fl(znorm + enorm) - 2*acc ).  k ascending within
    // a thread's scan; strict '<' keeps earliest index.
#pragma unroll
    for (int h = 0; h < 2; ++h)
#pragma unroll
      for (int cc = 0; cc < 4; ++cc) {
        const int k = kstart + h * 64 + tx * 4 + cc;
        const float nk = norms[k];
#pragma unroll
        for (int s = 0; s < 4; ++s)
#pragma unroll
          for (int rr = 0; rr < 4; ++rr) {
            const float t1 = zn[s][rr] + nk;
            const float sc = t1 - 2.0f * acc[s][rr][h][cc];
            if (sc < mv[s][rr]) { mv[s][rr] = sc; mi[s][rr] = k; }
          }
      }
  }
  // reduce across the 16 tx lanes of each ty group, then one u64 atomicMin/row
#pragma unroll
  for (int s = 0; s < 4; ++s)
#pragma unroll
    for (int rr = 0; rr < 4; ++rr) {
      unsigned long long p =
          ((unsigned long long)monof(mv[s][rr]) << 32) | (unsigned)mi[s][rr];
#pragma unroll
      for (int m = 1; m < 16; m <<= 1) {
        const unsigned long long o = __shfl_xor(p, m, 64);
        if (o < p) p = o;
      }
      if (tx == 0) atomicMin(&packed[nbase + s * 64 + ty * 4 + rr], p);
    }
}

// ---- K3: gather codes, write out (NCHW), idx floats, reduce SSE ----
__global__ __launch_bounds__(256)
void k_output(const float* __restrict__ z, const float* __restrict__ cb,
              const unsigned long long* __restrict__ packed,
              float* __restrict__ out, float* __restrict__ idxf,
              float* __restrict__ ssum) {
  __shared__ float zqT[256 * 33];
  __shared__ float part[4];
  const int t = threadIdx.x;
  const int blk = blockIdx.x;       // = b*32 + h
  const int nbase = blk * 32;

  {
    const int nl = t >> 3, m = t & 7;
    const int idx = (int)(packed[nbase + nl] & 0xFFFFFFFFull);
    const float* row = cb + (size_t)idx * Dd;
#pragma unroll
    for (int i = 0; i < 8; ++i) {
      const int d0 = m * 4 + i * 32;
      const float4 v = *(const float4*)(row + d0);
      zqT[(d0 + 0) * 33 + nl] = v.x;
      zqT[(d0 + 1) * 33 + nl] = v.y;
      zqT[(d0 + 2) * 33 + nl] = v.z;
      zqT[(d0 + 3) * 33 + nl] = v.w;
    }
    if (t < 32)
      idxf[nbase + t] = (float)(unsigned)(packed[nbase + t] & 0xFFFFFFFFull);
  }
  __syncthreads();

  const int w = t & 31, cg = t >> 5;
  const size_t base = (size_t)(blk >> 5) * 262144 + (size_t)(blk & 31) * 32 + w;
  float local = 0.f;
#pragma unroll
  for (int cc = 0; cc < 32; ++cc) {
    const int c = cg * 32 + cc;
    const float q  = zqT[c * 33 + w];
    const float zv = z[base + (size_t)c * 1024];
    out[base + (size_t)c * 1024] = q;
    const float dd = q - zv;
    local = fmaf(dd, dd, local);
  }
  float v = local;
#pragma unroll
  for (int m = 1; m < 64; m <<= 1) v += __shfl_xor(v, m, 64);
  if ((t & 63) == 0) part[t >> 6] = v;
  __syncthreads();
  if (t == 0) atomicAdd(ssum, part[0] + part[1] + part[2] + part[3]);
}

// ---- K4: finalize scalars ----
__global__ void k_final(const float* __restrict__ ssum, float* __restrict__ scal) {
  const float m = *ssum * INV_M;
  scal[0] = 1.25f * m;   // loss
  scal[1] = 0.25f * m;   // commitment_loss
  scal[2] = m;           // codebook_loss
}

extern "C" void kernel_launch(void* const* d_in, const int* in_sizes, int n_in,
                              void* d_out, int out_size, void* d_ws, size_t ws_size,
                              hipStream_t stream) {
  const float* z    = (const float*)d_in[0];
  const float* emb  = (const float*)d_in[1];
  const float* proj = (const float*)d_in[2];

  float* out  = (float*)d_out;
  float* scal = out + 4194304;
  float* idxf = out + 4194307;

  float* cbT   = (float*)d_ws;                 // 8 MB
  float* cb    = cbT + 2097152;                // 8 MB
  float* norms = cb + 2097152;                 // 32 KB
  unsigned long long* packed =
      (unsigned long long*)(norms + 8192);     // 128 KB
  float* ssum  = (float*)(packed + 16384);     // 4 B
  float* znorm = ssum + 1;                     // 64 KB

  hipMemsetAsync(packed, 0xFF, 16384 * sizeof(unsigned long long), stream);
  hipMemsetAsync(ssum, 0, sizeof(float), stream);

  k_codebook<<<dim3(128, 4), 256, 0, stream>>>(emb, proj, cb, cbT);
  k_norms   <<<32, 256, 0, stream>>>(cbT, norms);
  k_znorm   <<<64, 256, 0, stream>>>(z, znorm);
  k_argmin  <<<dim3(8, 64), 256, 0, stream>>>(z, cbT, norms, znorm, packed);
  k_output  <<<512, 256, 0, stream>>>(z, cb, packed, out, idxf, ssum);
  k_final   <<<1, 1, 0, stream>>>(ssum, scal);

  (void)in_sizes; (void)n_in; (void)out_size; (void)ws_size;
}

// Round 5
// 791.339 us; speedup vs baseline: 1.3771x; 1.3771x over previous
//
#include <hip/hip_runtime.h>
#include <cfloat>

// VQ forward, MI355X. z[16,256,32,32] f32, emb[8192,256] f32, proj[256,256] f32.
// N = 16384 rows, K = 8192 codes, D = 256.
// d_out (floats): out[4194304] | loss | commitment | codebook_loss | idx_as_float[16384]
// d_ws: cbT[256][8192] | cb[8192][256] | norms[8192] | packed_u64[16384] | ssum | znorm[16384]
//
// Correctness-critical: reference rounds d = (||z||^2 + ||e||^2) - 2*dot in fp32,
// quantizing scores to ulp(~256) ~ 1.5e-5; ties resolved by np.argmin first-index.
// We emulate the rounding exactly and tie-break via packed (monof(s)<<32|k) atomicMin.
//
// k_argmin R5: wave-uniform z (16 rows/wave via scalar loads, zero VGPR/LDS cost),
// e direct from global (lane*4 cols -> one coalesced dwordx4/j). No LDS, no barriers.
// acc = 16x4 = 64 VGPRs -> no spill under the 128-VGPR / 4-waves-per-SIMD target
// (R4 post-mortem: 128-reg acc + z-in-VGPR spilled 192 MB to scratch).

constexpr int Dd = 256;
constexpr int Kc = 8192;
constexpr float INV_M = 1.0f / 4194304.0f;

__device__ __forceinline__ unsigned monof(float f) {
  unsigned u = __float_as_uint(f);
  return (u & 0x80000000u) ? ~u : (u | 0x80000000u);
}

// ---- K1: codebook = emb @ proj^T, written as cb[k][d] and cbT[d][k] ----
__global__ __launch_bounds__(256)
void k_codebook(const float* __restrict__ emb, const float* __restrict__ proj,
                float* __restrict__ cb, float* __restrict__ cbT) {
  __shared__ float et[64 * 65];
  __shared__ float pt[64 * 65];
  const int t = threadIdx.x;
  const int tx = t & 15, ty = t >> 4;
  const int kb = blockIdx.x * 64;
  const int db = blockIdx.y * 64;
  float acc[4][4];
#pragma unroll
  for (int u = 0; u < 4; ++u)
#pragma unroll
    for (int v = 0; v < 4; ++v) acc[u][v] = 0.f;

  const int jm = t & 15;
  const int q  = t >> 4;

  for (int jc = 0; jc < Dd; jc += 64) {
    __syncthreads();
#pragma unroll
    for (int i = 0; i < 4; ++i) {
      const int row = q + i * 16;
      const float4 e4 = *(const float4*)(emb  + (size_t)(kb + row) * Dd + jc + jm * 4);
      const float4 p4 = *(const float4*)(proj + (size_t)(db + row) * Dd + jc + jm * 4);
      et[(jm*4 + 0) * 65 + row] = e4.x;
      et[(jm*4 + 1) * 65 + row] = e4.y;
      et[(jm*4 + 2) * 65 + row] = e4.z;
      et[(jm*4 + 3) * 65 + row] = e4.w;
      pt[(jm*4 + 0) * 65 + row] = p4.x;
      pt[(jm*4 + 1) * 65 + row] = p4.y;
      pt[(jm*4 + 2) * 65 + row] = p4.z;
      pt[(jm*4 + 3) * 65 + row] = p4.w;
    }
    __syncthreads();
#pragma unroll 16
    for (int j = 0; j < 64; ++j) {
      float a[4], b[4];
#pragma unroll
      for (int u = 0; u < 4; ++u) a[u] = et[j*65 + ty*4 + u];
#pragma unroll
      for (int v = 0; v < 4; ++v) b[v] = pt[j*65 + tx*4 + v];
#pragma unroll
      for (int u = 0; u < 4; ++u)
#pragma unroll
        for (int v = 0; v < 4; ++v) acc[u][v] = fmaf(a[u], b[v], acc[u][v]);
    }
  }
#pragma unroll
  for (int u = 0; u < 4; ++u) {
    const int k = kb + ty*4 + u;
#pragma unroll
    for (int v = 0; v < 4; ++v) {
      const int d = db + tx*4 + v;
      cb [(size_t)k * Dd + d] = acc[u][v];
      cbT[(size_t)d * Kc + k] = acc[u][v];
    }
  }
}

// ---- K1b: per-code squared norms ----
__global__ __launch_bounds__(256)
void k_norms(const float* __restrict__ cbT, float* __restrict__ norms) {
  const int k = blockIdx.x * 256 + threadIdx.x;
  float s = 0.f;
  for (int d = 0; d < Dd; ++d) {
    const float v = cbT[(size_t)d * Kc + k];
    s = fmaf(v, v, s);
  }
  norms[k] = s;
}

// ---- K1c: per-row ||z||^2, computed ONCE so all argmin blocks see identical bits ----
__global__ __launch_bounds__(256)
void k_znorm(const float* __restrict__ z, float* __restrict__ znorm) {
  const int n = blockIdx.x * 256 + threadIdx.x;
  const float* p = z + (size_t)(n >> 10) * 262144 + (n & 1023);
  float s = 0.f;
  for (int d = 0; d < Dd; ++d) {
    const float v = p[(size_t)d * 1024];
    s = fmaf(v, v, s);
  }
  znorm[n] = s;
}

// ---- K2: fused distance + argmin.  64 rows x 256 cols per block (256 thr) ----
// Wave w owns rows nbase + w*16 .. +15 (wave-uniform -> scalar loads).
// Lane l owns cols kbase + l*4 .. +3 (coalesced dwordx4 loads of cbT).
__global__ __launch_bounds__(256, 4)
void k_argmin(const float* __restrict__ z, const float* __restrict__ cbT,
              const float* __restrict__ norms, const float* __restrict__ znorm,
              unsigned long long* __restrict__ packed) {
  const int t    = threadIdx.x;
  const int lane = t & 63;
  const int kbase = blockIdx.x * 256;
  const int nbase = blockIdx.y * 64;     // 64-row slab: single batch, contiguous hw

  // wave-uniform row base (readfirstlane pins it to an SGPR)
  const int wrow = __builtin_amdgcn_readfirstlane((t >> 6) * 16);

  // uniform pointer to this wave's 16 z rows (consecutive hw) for each d
  const float* zw = z + (size_t)(nbase >> 10) * 262144 + (nbase & 1023) + wrow;
  // per-lane pointer to its 4 codebook columns for each d
  const float* ge = cbT + kbase + lane * 4;

  float acc[16][4];
#pragma unroll
  for (int r = 0; r < 16; ++r)
#pragma unroll
    for (int c = 0; c < 4; ++c) acc[r][c] = 0.f;

#pragma unroll 2
  for (int j = 0; j < Dd; ++j) {
    const float4 e4 = *(const float4*)(ge + (size_t)j * Kc);
    const float ec[4] = {e4.x, e4.y, e4.z, e4.w};
    const float* zp = zw + (size_t)j * 1024;
#pragma unroll
    for (int r = 0; r < 16; ++r) {
      const float zr = zp[r];            // wave-uniform -> s_load
#pragma unroll
      for (int c = 0; c < 4; ++c)
        acc[r][c] = fmaf(zr, ec[c], acc[r][c]);
    }
  }

  // norms for this lane's 4 cols; znorm for the wave's 16 rows (uniform)
  const float4 n4 = *(const float4*)(norms + kbase + lane * 4);
  const float nk[4] = {n4.x, n4.y, n4.z, n4.w};
  const float* znw = znorm + nbase + wrow;

  // Quantized fold: s = fl( fl(znorm + enorm) - 2*acc ).  c ascending => k
  // ascending within a lane; packed u64 min => global first-index tie-break.
#pragma unroll
  for (int r = 0; r < 16; ++r) {
    const float znr = znw[r];
    float mvr = FLT_MAX;
    int   mir = 0;
#pragma unroll
    for (int c = 0; c < 4; ++c) {
      const float t1 = znr + nk[c];
      const float sc = t1 - 2.0f * acc[r][c];
      if (sc < mvr) { mvr = sc; mir = kbase + lane * 4 + c; }
    }
    unsigned long long p =
        ((unsigned long long)monof(mvr) << 32) | (unsigned)mir;
#pragma unroll
    for (int m = 1; m < 64; m <<= 1) {
      const unsigned long long o = __shfl_xor(p, m, 64);
      if (o < p) p = o;
    }
    if (lane == 0) atomicMin(&packed[nbase + wrow + r], p);
  }
}

// ---- K3: gather codes, write out (NCHW), idx floats, reduce SSE ----
__global__ __launch_bounds__(256)
void k_output(const float* __restrict__ z, const float* __restrict__ cb,
              const unsigned long long* __restrict__ packed,
              float* __restrict__ out, float* __restrict__ idxf,
              float* __restrict__ ssum) {
  __shared__ float zqT[256 * 33];
  __shared__ float part[4];
  const int t = threadIdx.x;
  const int blk = blockIdx.x;       // = b*32 + h
  const int nbase = blk * 32;

  {
    const int nl = t >> 3, m = t & 7;
    const int idx = (int)(packed[nbase + nl] & 0xFFFFFFFFull);
    const float* row = cb + (size_t)idx * Dd;
#pragma unroll
    for (int i = 0; i < 8; ++i) {
      const int d0 = m * 4 + i * 32;
      const float4 v = *(const float4*)(row + d0);
      zqT[(d0 + 0) * 33 + nl] = v.x;
      zqT[(d0 + 1) * 33 + nl] = v.y;
      zqT[(d0 + 2) * 33 + nl] = v.z;
      zqT[(d0 + 3) * 33 + nl] = v.w;
    }
    if (t < 32)
      idxf[nbase + t] = (float)(unsigned)(packed[nbase + t] & 0xFFFFFFFFull);
  }
  __syncthreads();

  const int w = t & 31, cg = t >> 5;
  const size_t base = (size_t)(blk >> 5) * 262144 + (size_t)(blk & 31) * 32 + w;
  float local = 0.f;
#pragma unroll
  for (int cc = 0; cc < 32; ++cc) {
    const int c = cg * 32 + cc;
    const float q  = zqT[c * 33 + w];
    const float zv = z[base + (size_t)c * 1024];
    out[base + (size_t)c * 1024] = q;
    const float dd = q - zv;
    local = fmaf(dd, dd, local);
  }
  float v = local;
#pragma unroll
  for (int m = 1; m < 64; m <<= 1) v += __shfl_xor(v, m, 64);
  if ((t & 63) == 0) part[t >> 6] = v;
  __syncthreads();
  if (t == 0) atomicAdd(ssum, part[0] + part[1] + part[2] + part[3]);
}

// ---- K4: finalize scalars ----
__global__ void k_final(const float* __restrict__ ssum, float* __restrict__ scal) {
  const float m = *ssum * INV_M;
  scal[0] = 1.25f * m;   // loss
  scal[1] = 0.25f * m;   // commitment_loss
  scal[2] = m;           // codebook_loss
}

extern "C" void kernel_launch(void* const* d_in, const int* in_sizes, int n_in,
                              void* d_out, int out_size, void* d_ws, size_t ws_size,
                              hipStream_t stream) {
  const float* z    = (const float*)d_in[0];
  const float* emb  = (const float*)d_in[1];
  const float* proj = (const float*)d_in[2];

  float* out  = (float*)d_out;
  float* scal = out + 4194304;
  float* idxf = out + 4194307;

  float* cbT   = (float*)d_ws;                 // 8 MB
  float* cb    = cbT + 2097152;                // 8 MB
  float* norms = cb + 2097152;                 // 32 KB
  unsigned long long* packed =
      (unsigned long long*)(norms + 8192);     // 128 KB
  float* ssum  = (float*)(packed + 16384);     // 4 B
  float* znorm = ssum + 1;                     // 64 KB

  hipMemsetAsync(packed, 0xFF, 16384 * sizeof(unsigned long long), stream);
  hipMemsetAsync(ssum, 0, sizeof(float), stream);

  k_codebook<<<dim3(128, 4), 256, 0, stream>>>(emb, proj, cb, cbT);
  k_norms   <<<32, 256, 0, stream>>>(cbT, norms);
  k_znorm   <<<64, 256, 0, stream>>>(z, znorm);
  k_argmin  <<<dim3(32, 256), 256, 0, stream>>>(z, cbT, norms, znorm, packed);
  k_output  <<<512, 256, 0, stream>>>(z, cb, packed, out, idxf, ssum);
  k_final   <<<1, 1, 0, stream>>>(ssum, scal);

  (void)in_sizes; (void)n_in; (void)out_size; (void)ws_size;
}